// Round 5
// baseline (215.884 us; speedup 1.0000x reference)
//
#include <hip/hip_runtime.h>
#include <hip/hip_bf16.h>
#include <math.h>

#define N 8192
#define D 256
#define MARGIN 1.0f

#define BM 128
#define BN 128
#define NCH 4            // k-chunks of 64 bf16 elems (128B per row per plane)
#define NB (N / BM)      // 64
#define NTRI (NB * (NB + 1) / 2)   // 2080
#define BCAP 64          // class bucket capacity

typedef __attribute__((ext_vector_type(8))) short bhalf8;
typedef __attribute__((ext_vector_type(4))) float f32x4;

__device__ __forceinline__ unsigned short f2bf(float f) {
    return __builtin_bit_cast(unsigned short, __float2bfloat16(f));
}
__device__ __forceinline__ float bf2f(unsigned short u) {
    return __bfloat162float(__builtin_bit_cast(__hip_bfloat16, u));
}

// ---------------------------------------------------------------------------
__global__ void k_zero(int* __restrict__ cnt) {
    cnt[threadIdx.x] = 0;
}

// ---------------------------------------------------------------------------
// split x into hi/lo bf16 planes + build class buckets
// ---------------------------------------------------------------------------
__global__ __launch_bounds__(256) void k_conv(const float* __restrict__ x,
                                              const int* __restrict__ labels,
                                              unsigned short* __restrict__ hi,
                                              unsigned short* __restrict__ lo,
                                              int* __restrict__ cnt,
                                              int* __restrict__ bkt) {
    int i = blockIdx.x * 256 + threadIdx.x;
    float4 v = reinterpret_cast<const float4*>(x)[i];
    ushort4 h, l;
    h.x = f2bf(v.x); l.x = f2bf(v.x - bf2f(h.x));
    h.y = f2bf(v.y); l.y = f2bf(v.y - bf2f(h.y));
    h.z = f2bf(v.z); l.z = f2bf(v.z - bf2f(h.z));
    h.w = f2bf(v.w); l.w = f2bf(v.w - bf2f(h.w));
    reinterpret_cast<ushort4*>(hi)[i] = h;
    reinterpret_cast<ushort4*>(lo)[i] = l;
    if (i < N) {
        int lb = labels[i];
        int p = atomicAdd(&cnt[lb], 1);
        if (p < BCAP) bkt[lb * BCAP + p] = i;
    }
}

// ---------------------------------------------------------------------------
// one wave per anchor; visit only classmates via buckets (exact f32 path)
// ---------------------------------------------------------------------------
__global__ __launch_bounds__(256) void k_dpos(const float* __restrict__ x,
                                              const int* __restrict__ labels,
                                              const int* __restrict__ cnt,
                                              const int* __restrict__ bkt,
                                              float* __restrict__ sq,
                                              float* __restrict__ dpos,
                                              int* __restrict__ minneg,
                                              int* __restrict__ minsemi) {
    int wave = (blockIdx.x * blockDim.x + threadIdx.x) >> 6;
    int lane = threadIdx.x & 63;
    if (wave >= N) return;
    const int i = wave;

    float4 xi = reinterpret_cast<const float4*>(x + (size_t)i * D)[lane];
    float sqi = xi.x * xi.x + xi.y * xi.y + xi.z * xi.z + xi.w * xi.w;
    for (int m = 32; m >= 1; m >>= 1) sqi += __shfl_xor(sqi, m, 64);

    const int L = labels[i];
    int c = cnt[L]; if (c > BCAP) c = BCAP;
    float dp = -1.0f;

    for (int e = 0; e < c; ++e) {
        int j = bkt[L * BCAP + e];
        if (j == i) continue;
        float4 xj = reinterpret_cast<const float4*>(x + (size_t)j * D)[lane];
        float dotp = xi.x * xj.x + xi.y * xj.y + xi.z * xj.z + xi.w * xj.w;
        float sqjp = xj.x * xj.x + xj.y * xj.y + xj.z * xj.z + xj.w * xj.w;
        for (int m = 32; m >= 1; m >>= 1) {
            dotp += __shfl_xor(dotp, m, 64);
            sqjp += __shfl_xor(sqjp, m, 64);
        }
        float sqd = fmaxf(sqi + sqjp - 2.0f * dotp, 0.0f);
        float dist = sqd > 0.0f ? sqrtf(sqd) : 0.0f;
        dp = fmaxf(dp, dist);
    }

    if (lane == 0) {
        sq[i] = sqi;
        dpos[i] = dp;
        minneg[i] = 0x7F800000;
        minsemi[i] = 0x7F800000;
    }
}

// ---------------------------------------------------------------------------
// symmetric bf16-split MFMA GEMM, pipelined single-buffer schedule.
// 4 LDS buffers (Ah/Al/Bh/Bl, 16KB each), staged per-plane with contiguous
// 128B rows (round-3 proven swizzle, 0 bank conflicts). Pipeline: a buffer
// is dead once its fragments are in registers, so next chunk's loads are
// issued right after the consuming ds_reads + barrier; counted vmcnt keeps
// them in flight under the MFMA clusters.
// ---------------------------------------------------------------------------
__global__ __launch_bounds__(256) void k_main(const unsigned short* __restrict__ hi,
                                              const unsigned short* __restrict__ lo,
                                              const int* __restrict__ labels,
                                              const float* __restrict__ sq,
                                              const float* __restrict__ dpos,
                                              int* __restrict__ minneg,
                                              int* __restrict__ minsemi) {
    __shared__ char Ah[BM * 128];   // 16 KB each
    __shared__ char Al[BM * 128];
    __shared__ char Bh[BN * 128];
    __shared__ char Bl[BN * 128];
    __shared__ float rsq[BM], csq[BN];
    __shared__ float rdp2a[BM], rdp2b[BM], cdp2a[BN], cdp2b[BN];
    __shared__ int rlab[BM], clab[BN];

    const int t = threadIdx.x;
    int tb = blockIdx.x;
    // triangular decode: tb -> (by, bx), by <= bx
    int by = (int)((2 * NB + 1 - sqrtf((float)((2 * NB + 1) * (2 * NB + 1)) -
                                       8.0f * (float)tb)) * 0.5f);
    if (by < 0) by = 0;
    if (by > NB - 1) by = NB - 1;
    while (by > 0 && (by * NB - by * (by - 1) / 2) > tb) --by;
    while (((by + 1) * NB - (by + 1) * by / 2) <= tb) ++by;
    const int bx = by + (tb - (by * NB - by * (by - 1) / 2));
    const int r0 = by * BM, c0 = bx * BN;

    const int w = t >> 6, lane = t & 63;
    const int wr = w >> 1, wc = w & 1;

    if (t < BM) {
        rlab[t] = labels[r0 + t];
        rsq[t] = sq[r0 + t];
        float dp = dpos[r0 + t];
        rdp2a[t] = dp * dp;
        float dh = dp + MARGIN;
        rdp2b[t] = dh * dh;
    } else {
        int u = t - BM;
        clab[u] = labels[c0 + u];
        csq[u] = sq[c0 + u];
        float dp = dpos[c0 + u];
        cdp2a[u] = dp * dp;
        float dh = dp + MARGIN;
        cdp2b[u] = dh * dh;
    }

    f32x4 acc[4][4] = {};

    // staging geometry (round-3 proven): per buffer, wave w writes chunks
    // q*4+w (1KB each); row = chunk*8 + (lane>>3); 16B slot pre-swizzled in
    // the global source so the LDS dest stays linear.
    const int srow = lane >> 3;
    const int scol = ((lane & 7) ^ srow) << 3;   // k-elem offset (16B units)

#define STAGE_PAIR(bufA, bufB, plane, k0e)                                      \
    {                                                                           \
        _Pragma("unroll")                                                       \
        for (int q = 0; q < 4; ++q) {                                           \
            int chunk = q * 4 + w;                                              \
            int row = chunk * 8 + srow;                                         \
            const unsigned short* gpa = (plane) + (size_t)(r0 + row) * D + (k0e) + scol; \
            const unsigned short* gpb = (plane) + (size_t)(c0 + row) * D + (k0e) + scol; \
            char* lpa = (bufA) + chunk * 1024 + lane * 16;                      \
            char* lpb = (bufB) + chunk * 1024 + lane * 16;                      \
            __builtin_amdgcn_global_load_lds(                                   \
                (__attribute__((address_space(1))) void*)(void*)gpa,            \
                (__attribute__((address_space(3))) void*)lpa, 16, 0, 0);        \
            __builtin_amdgcn_global_load_lds(                                   \
                (__attribute__((address_space(1))) void*)(void*)gpb,            \
                (__attribute__((address_space(3))) void*)lpb, 16, 0, 0);        \
        }                                                                       \
    }

    // prologue: both planes of chunk 0 (16 ops/wave: 8 HB then 8 LB)
    STAGE_PAIR(Ah, Bh, hi, 0);
    STAGE_PAIR(Al, Bl, lo, 0);

    const int g2 = lane >> 4;          // 16B k-subslot / epilogue row group
    const int lr = lane & 15;
    const int rsw = lr & 7;            // row XOR term (rows are +mult of 8)

#pragma unroll 1
    for (int s = 0; s < NCH; ++s) {
        // HB(s) are the 8 oldest outstanding ops; LB(s) (8) may stay in flight
        asm volatile("s_waitcnt vmcnt(8)" ::: "memory");
        __builtin_amdgcn_s_barrier();

        bhalf8 aH[2][4], bH[2][4];
#pragma unroll
        for (int kk = 0; kk < 2; ++kk) {
            const int cb = kk * 64 + (g2 << 4);
#pragma unroll
            for (int m = 0; m < 4; ++m) {
                int ra = wr * 64 + m * 16 + lr;
                int rb = wc * 64 + m * 16 + lr;
                aH[kk][m] = *reinterpret_cast<const bhalf8*>(Ah + ra * 128 + (cb ^ (rsw << 4)));
                bH[kk][m] = *reinterpret_cast<const bhalf8*>(Bh + rb * 128 + (cb ^ (rsw << 4)));
            }
        }
        asm volatile("s_waitcnt lgkmcnt(0)" ::: "memory");
        __builtin_amdgcn_s_barrier();            // all waves hold Ah/Bh in regs
        if (s < NCH - 1) STAGE_PAIR(Ah, Bh, hi, (s + 1) * 64);

#pragma unroll
        for (int kk = 0; kk < 2; ++kk)
#pragma unroll
            for (int m = 0; m < 4; ++m)
#pragma unroll
                for (int n = 0; n < 4; ++n)
                    acc[m][n] = __builtin_amdgcn_mfma_f32_16x16x32_bf16(
                        aH[kk][m], bH[kk][n], acc[m][n], 0, 0, 0);

        // LB(s) retired (8 oldest); HB(s+1) (8) stays in flight
        if (s < NCH - 1)
            asm volatile("s_waitcnt vmcnt(8)" ::: "memory");
        else
            asm volatile("s_waitcnt vmcnt(0)" ::: "memory");
        __builtin_amdgcn_s_barrier();

        bhalf8 aL[2][4], bL[2][4];
#pragma unroll
        for (int kk = 0; kk < 2; ++kk) {
            const int cb = kk * 64 + (g2 << 4);
#pragma unroll
            for (int m = 0; m < 4; ++m) {
                int ra = wr * 64 + m * 16 + lr;
                int rb = wc * 64 + m * 16 + lr;
                aL[kk][m] = *reinterpret_cast<const bhalf8*>(Al + ra * 128 + (cb ^ (rsw << 4)));
                bL[kk][m] = *reinterpret_cast<const bhalf8*>(Bl + rb * 128 + (cb ^ (rsw << 4)));
            }
        }
        asm volatile("s_waitcnt lgkmcnt(0)" ::: "memory");
        __builtin_amdgcn_s_barrier();            // all waves hold Al/Bl in regs
        if (s < NCH - 1) STAGE_PAIR(Al, Bl, lo, (s + 1) * 64);

#pragma unroll
        for (int kk = 0; kk < 2; ++kk)
#pragma unroll
            for (int m = 0; m < 4; ++m)
#pragma unroll
                for (int n = 0; n < 4; ++n)
                    acc[m][n] = __builtin_amdgcn_mfma_f32_16x16x32_bf16(
                        aH[kk][m], bL[kk][n], acc[m][n], 0, 0, 0);
#pragma unroll
        for (int kk = 0; kk < 2; ++kk)
#pragma unroll
            for (int m = 0; m < 4; ++m)
#pragma unroll
                for (int n = 0; n < 4; ++n)
                    acc[m][n] = __builtin_amdgcn_mfma_f32_16x16x32_bf16(
                        aL[kk][m], bH[kk][n], acc[m][n], 0, 0, 0);
    }
#undef STAGE_PAIR

    // ---- epilogue: squared-distance space ----
    const float INF = __builtin_inff();

    // row pass: per row, min over this wave's 64 cols
#pragma unroll
    for (int m = 0; m < 4; ++m) {
#pragma unroll
        for (int reg = 0; reg < 4; ++reg) {
            const int row = wr * 64 + m * 16 + g2 * 4 + reg;
            const float si = rsq[row];
            const int rl = rlab[row];
            const float dp2 = rdp2a[row], dphi2 = rdp2b[row];
            float mn = INF, ms = INF;
#pragma unroll
            for (int nn = 0; nn < 4; ++nn) {
                const int col = wc * 64 + nn * 16 + lr;
                float sqd = fmaxf(si + csq[col] - 2.0f * acc[m][nn][reg], 0.0f);
                bool neq = (rl != clab[col]);
                mn = fminf(mn, neq ? sqd : INF);
                bool semi = neq && (sqd > dp2) && (sqd < dphi2);
                ms = fminf(ms, semi ? sqd : INF);
            }
#pragma unroll
            for (int msk = 1; msk <= 8; msk <<= 1) {
                mn = fminf(mn, __shfl_xor(mn, msk, 64));
                ms = fminf(ms, __shfl_xor(ms, msk, 64));
            }
            if (lr == 0) {
                atomicMin(&minneg[r0 + row], __float_as_int(mn));
                atomicMin(&minsemi[r0 + row], __float_as_int(ms));
            }
        }
    }

    // col pass: per col, min over this wave's 64 rows
#pragma unroll
    for (int n = 0; n < 4; ++n) {
        const int col = wc * 64 + n * 16 + lr;
        const float sj = csq[col];
        const int cl = clab[col];
        const float dp2 = cdp2a[col], dphi2 = cdp2b[col];
        float mn = INF, ms = INF;
#pragma unroll
        for (int m = 0; m < 4; ++m) {
#pragma unroll
            for (int reg = 0; reg < 4; ++reg) {
                const int row = wr * 64 + m * 16 + g2 * 4 + reg;
                float sqd = fmaxf(rsq[row] + sj - 2.0f * acc[m][n][reg], 0.0f);
                bool neq = (cl != rlab[row]);
                mn = fminf(mn, neq ? sqd : INF);
                bool semi = neq && (sqd > dp2) && (sqd < dphi2);
                ms = fminf(ms, semi ? sqd : INF);
            }
        }
        mn = fminf(mn, __shfl_xor(mn, 16, 64));
        mn = fminf(mn, __shfl_xor(mn, 32, 64));
        ms = fminf(ms, __shfl_xor(ms, 16, 64));
        ms = fminf(ms, __shfl_xor(ms, 32, 64));
        if (g2 == 0) {
            atomicMin(&minneg[c0 + col], __float_as_int(mn));
            atomicMin(&minsemi[c0 + col], __float_as_int(ms));
        }
    }
}

// ---------------------------------------------------------------------------
// final scalar reduction (minima are SQUARED distances)
// ---------------------------------------------------------------------------
__global__ __launch_bounds__(1024) void k_final(const float* __restrict__ dpos,
                                                const int* __restrict__ minneg,
                                                const int* __restrict__ minsemi,
                                                float* __restrict__ out) {
    __shared__ float ssum[1024];
    __shared__ float scnt[1024];
    int t = threadIdx.x;
    float s = 0.0f, cn = 0.0f;
    for (int i = t; i < N; i += 1024) {
        float dp = dpos[i];
        float mnq = __int_as_float(minneg[i]);
        float msq = __int_as_float(minsemi[i]);
        bool has_pos = dp >= 0.0f;
        bool has_neg = mnq < __builtin_inff();
        if (has_pos && has_neg) {
            float dnq = (msq < __builtin_inff()) ? msq : mnq;
            float dn = sqrtf(dnq);
            s += fmaxf(dp - dn + MARGIN, 0.0f);
            cn += 1.0f;
        }
    }
    ssum[t] = s;
    scnt[t] = cn;
    __syncthreads();
    for (int off = 512; off >= 1; off >>= 1) {
        if (t < off) {
            ssum[t] += ssum[t + off];
            scnt[t] += scnt[t + off];
        }
        __syncthreads();
    }
    if (t == 0) out[0] = ssum[0] / scnt[0];
}

// ---------------------------------------------------------------------------
extern "C" void kernel_launch(void* const* d_in, const int* in_sizes, int n_in,
                              void* d_out, int out_size, void* d_ws, size_t ws_size,
                              hipStream_t stream) {
    const float* x = (const float*)d_in[0];
    const int* labels = (const int*)d_in[1];
    float* out = (float*)d_out;

    // ws: sq[N] | dpos[N] | minneg[N] | minsemi[N] | cnt[512] | bkt[512*64]
    //     | hi[N*D] bf16 | lo[N*D] bf16
    float* sq = (float*)d_ws;
    float* dpos = sq + N;
    int* minneg = (int*)(dpos + N);
    int* minsemi = minneg + N;
    int* cnt = minsemi + N;
    int* bkt = cnt + 512;
    unsigned short* hi = (unsigned short*)(bkt + 512 * BCAP);
    unsigned short* lo = hi + (size_t)N * D;

    hipLaunchKernelGGL(k_zero, dim3(1), dim3(512), 0, stream, cnt);
    hipLaunchKernelGGL(k_conv, dim3(N * D / 4 / 256), dim3(256), 0, stream,
                       x, labels, hi, lo, cnt, bkt);
    hipLaunchKernelGGL(k_dpos, dim3(N / 4), dim3(256), 0, stream,
                       x, labels, cnt, bkt, sq, dpos, minneg, minsemi);
    hipLaunchKernelGGL(k_main, dim3(NTRI), dim3(256), 0, stream,
                       hi, lo, labels, sq, dpos, minneg, minsemi);
    hipLaunchKernelGGL(k_final, dim3(1), dim3(1024), 0, stream,
                       dpos, minneg, minsemi, out);
}

// Round 6
// 169.095 us; speedup vs baseline: 1.2767x; 1.2767x over previous
//
#include <hip/hip_runtime.h>
#include <hip/hip_bf16.h>
#include <math.h>

#define N 8192
#define D 256
#define MARGIN 1.0f

#define BM 128
#define BN 128
#define NCH 4            // k-chunks of 64 bf16 elems (128B per row per plane)
#define NB (N / BM)      // 64
#define NTRI (NB * (NB + 1) / 2)   // 2080
#define BCAP 64          // class bucket capacity

typedef __attribute__((ext_vector_type(8))) short bhalf8;
typedef __attribute__((ext_vector_type(4))) float f32x4;

__device__ __forceinline__ unsigned short f2bf(float f) {
    return __builtin_bit_cast(unsigned short, __float2bfloat16(f));
}
__device__ __forceinline__ float bf2f(unsigned short u) {
    return __bfloat162float(__builtin_bit_cast(__hip_bfloat16, u));
}

// ---------------------------------------------------------------------------
__global__ void k_zero(int* __restrict__ cnt) {
    cnt[threadIdx.x] = 0;
}

// ---------------------------------------------------------------------------
// split x into hi/lo bf16 planes + build class buckets
// ---------------------------------------------------------------------------
__global__ __launch_bounds__(256) void k_conv(const float* __restrict__ x,
                                              const int* __restrict__ labels,
                                              unsigned short* __restrict__ hi,
                                              unsigned short* __restrict__ lo,
                                              int* __restrict__ cnt,
                                              int* __restrict__ bkt) {
    int i = blockIdx.x * 256 + threadIdx.x;
    float4 v = reinterpret_cast<const float4*>(x)[i];
    ushort4 h, l;
    h.x = f2bf(v.x); l.x = f2bf(v.x - bf2f(h.x));
    h.y = f2bf(v.y); l.y = f2bf(v.y - bf2f(h.y));
    h.z = f2bf(v.z); l.z = f2bf(v.z - bf2f(h.z));
    h.w = f2bf(v.w); l.w = f2bf(v.w - bf2f(h.w));
    reinterpret_cast<ushort4*>(hi)[i] = h;
    reinterpret_cast<ushort4*>(lo)[i] = l;
    if (i < N) {
        int lb = labels[i];
        int p = atomicAdd(&cnt[lb], 1);
        if (p < BCAP) bkt[lb * BCAP + p] = i;
    }
}

// ---------------------------------------------------------------------------
// one wave per anchor; visit only classmates via buckets (exact f32 path)
// ---------------------------------------------------------------------------
__global__ __launch_bounds__(256) void k_dpos(const float* __restrict__ x,
                                              const int* __restrict__ labels,
                                              const int* __restrict__ cnt,
                                              const int* __restrict__ bkt,
                                              float* __restrict__ sq,
                                              float* __restrict__ dpos,
                                              int* __restrict__ minneg,
                                              int* __restrict__ minsemi) {
    int wave = (blockIdx.x * blockDim.x + threadIdx.x) >> 6;
    int lane = threadIdx.x & 63;
    if (wave >= N) return;
    const int i = wave;

    float4 xi = reinterpret_cast<const float4*>(x + (size_t)i * D)[lane];
    float sqi = xi.x * xi.x + xi.y * xi.y + xi.z * xi.z + xi.w * xi.w;
    for (int m = 32; m >= 1; m >>= 1) sqi += __shfl_xor(sqi, m, 64);

    const int L = labels[i];
    int c = cnt[L]; if (c > BCAP) c = BCAP;
    float dp = -1.0f;

    for (int e = 0; e < c; ++e) {
        int j = bkt[L * BCAP + e];
        if (j == i) continue;
        float4 xj = reinterpret_cast<const float4*>(x + (size_t)j * D)[lane];
        float dotp = xi.x * xj.x + xi.y * xj.y + xi.z * xj.z + xi.w * xj.w;
        float sqjp = xj.x * xj.x + xj.y * xj.y + xj.z * xj.z + xj.w * xj.w;
        for (int m = 32; m >= 1; m >>= 1) {
            dotp += __shfl_xor(dotp, m, 64);
            sqjp += __shfl_xor(sqjp, m, 64);
        }
        float sqd = fmaxf(sqi + sqjp - 2.0f * dotp, 0.0f);
        float dist = sqd > 0.0f ? sqrtf(sqd) : 0.0f;
        dp = fmaxf(dp, dist);
    }

    if (lane == 0) {
        sq[i] = sqi;
        dpos[i] = dp;
        minneg[i] = 0x7F800000;
        minsemi[i] = 0x7F800000;
    }
}

// ---------------------------------------------------------------------------
// symmetric bf16-split MFMA GEMM, rotating 3-slot LDS schedule (52 KB ->
// 3 blocks/CU). Slot lifetimes per chunk: Ah dies after hl, Bh after lh,
// Bl after hl -> per chunk: [vmcnt(4) bar] hh(pA*pB) -> [vmcnt(0) bar]
// hl(pA*pC) -> stage pA<-Al, pC<-Ah' -> [vmcnt(4) bar] lh(pA*pB) ->
// stage pB<-Bh', pA<-Bl' -> swap(pA,pC). Counted vmcnt keeps newest
// stage in flight across phases. Per-phase 8-frag reads keep VGPR <= ~112
// (r5's 136-VGPR cliff avoided).
// ---------------------------------------------------------------------------
__global__ __launch_bounds__(256) void k_main(const unsigned short* __restrict__ hi,
                                              const unsigned short* __restrict__ lo,
                                              const int* __restrict__ labels,
                                              const float* __restrict__ sq,
                                              const float* __restrict__ dpos,
                                              int* __restrict__ minneg,
                                              int* __restrict__ minsemi) {
    __shared__ char S0[BM * 128];   // 16 KB each, 48 KB total
    __shared__ char S1[BM * 128];
    __shared__ char S2[BM * 128];
    __shared__ float rsq[BM], csq[BN];
    __shared__ float rdp2a[BM], rdp2b[BM], cdp2a[BN], cdp2b[BN];
    __shared__ int rlab[BM], clab[BN];

    const int t = threadIdx.x;
    int tb = blockIdx.x;
    // triangular decode: tb -> (by, bx), by <= bx
    int by = (int)((2 * NB + 1 - sqrtf((float)((2 * NB + 1) * (2 * NB + 1)) -
                                       8.0f * (float)tb)) * 0.5f);
    if (by < 0) by = 0;
    if (by > NB - 1) by = NB - 1;
    while (by > 0 && (by * NB - by * (by - 1) / 2) > tb) --by;
    while (((by + 1) * NB - (by + 1) * by / 2) <= tb) ++by;
    const int bx = by + (tb - (by * NB - by * (by - 1) / 2));
    const int r0 = by * BM, c0 = bx * BN;

    const int w = t >> 6, lane = t & 63;
    const int wr = w >> 1, wc = w & 1;

    if (t < BM) {
        rlab[t] = labels[r0 + t];
        rsq[t] = sq[r0 + t];
        float dp = dpos[r0 + t];
        rdp2a[t] = dp * dp;
        float dh = dp + MARGIN;
        rdp2b[t] = dh * dh;
    } else {
        int u = t - BM;
        clab[u] = labels[c0 + u];
        csq[u] = sq[c0 + u];
        float dp = dpos[c0 + u];
        cdp2a[u] = dp * dp;
        float dh = dp + MARGIN;
        cdp2b[u] = dh * dh;
    }

    f32x4 acc[4][4] = {};

    // staging geometry (r3-proven): 16 chunks of 1KB per buffer; wave w does
    // chunks q*4+w; row = chunk*8 + (lane>>3); 16B slot pre-swizzled in the
    // global source so the LDS dest stays linear. 4 gl_lds per wave per buf.
    const int srow = lane >> 3;
    const int scol = ((lane & 7) ^ srow) << 3;   // k-elem offset (16B units)

#define STAGE1(buf, plane, base, k0e)                                           \
    {                                                                           \
        _Pragma("unroll")                                                       \
        for (int q = 0; q < 4; ++q) {                                           \
            int chunk = q * 4 + w;                                              \
            int row = chunk * 8 + srow;                                         \
            const unsigned short* gp = (plane) + (size_t)((base) + row) * D + (k0e) + scol; \
            char* lp = (buf) + chunk * 1024 + lane * 16;                        \
            __builtin_amdgcn_global_load_lds(                                   \
                (__attribute__((address_space(1))) void*)(void*)gp,             \
                (__attribute__((address_space(3))) void*)lp, 16, 0, 0);         \
        }                                                                       \
    }

    const int g2 = lane >> 4;          // 16B k-subslot / epilogue row group
    const int lr = lane & 15;
    const int rsw = lr & 7;            // row XOR term (rows are +mult of 8)

#define PHASE(PA, PB)                                                           \
    {                                                                           \
        _Pragma("unroll")                                                       \
        for (int kk = 0; kk < 2; ++kk) {                                        \
            bhalf8 aF[4], bF[4];                                                \
            const int cb = kk * 64 + (g2 << 4);                                 \
            _Pragma("unroll")                                                   \
            for (int m = 0; m < 4; ++m) {                                       \
                int ra = wr * 64 + m * 16 + lr;                                 \
                int rb = wc * 64 + m * 16 + lr;                                 \
                aF[m] = *reinterpret_cast<const bhalf8*>((PA) + ra * 128 + (cb ^ (rsw << 4))); \
                bF[m] = *reinterpret_cast<const bhalf8*>((PB) + rb * 128 + (cb ^ (rsw << 4))); \
            }                                                                   \
            _Pragma("unroll")                                                   \
            for (int m = 0; m < 4; ++m)                                         \
                _Pragma("unroll")                                               \
                for (int n = 0; n < 4; ++n)                                     \
                    acc[m][n] = __builtin_amdgcn_mfma_f32_16x16x32_bf16(        \
                        aF[m], bF[n], acc[m][n], 0, 0, 0);                      \
        }                                                                       \
    }

    char* pA = S0;   // Ah(s)   (after hl: Al(s); role swaps with pC each chunk)
    char* pB = S1;   // Bh(s)
    char* pC = S2;   // Bl(s)   (becomes Ah(s+1) carrier)

    STAGE1(pA, hi, r0, 0);      // Ah(0)
    STAGE1(pB, hi, c0, 0);      // Bh(0)
    STAGE1(pC, lo, c0, 0);      // Bl(0)

#pragma unroll 1
    for (int s = 0; s < NCH; ++s) {
        const int k0 = s * 64;

        // === hh: pA(Ah) * pB(Bh). Outstanding: [Ah(4),Bh(4),Bl(4)] -> keep Bl.
        asm volatile("s_waitcnt vmcnt(4)" ::: "memory");
        __builtin_amdgcn_s_barrier();
        PHASE(pA, pB);

        // === hl: pA(Ah) * pC(Bl). Only Bl outstanding.
        asm volatile("s_waitcnt vmcnt(0)" ::: "memory");
        __builtin_amdgcn_s_barrier();
        PHASE(pA, pC);

        // all waves done reading pA/pC -> both slots restageable
        asm volatile("s_waitcnt lgkmcnt(0)" ::: "memory");
        __builtin_amdgcn_sched_barrier(0);
        __builtin_amdgcn_s_barrier();
        STAGE1(pA, lo, r0, k0);                          // Al(s)
        if (s < NCH - 1) STAGE1(pC, hi, r0, k0 + 64);    // Ah(s+1)

        // === lh: pA(Al) * pB(Bh). Wait Al (oldest 4), keep Ah' in flight.
        if (s < NCH - 1)
            asm volatile("s_waitcnt vmcnt(4)" ::: "memory");
        else
            asm volatile("s_waitcnt vmcnt(0)" ::: "memory");
        __builtin_amdgcn_s_barrier();
        PHASE(pA, pB);

        if (s < NCH - 1) {
            // all waves done reading pA/pB -> restage for next chunk
            asm volatile("s_waitcnt lgkmcnt(0)" ::: "memory");
            __builtin_amdgcn_sched_barrier(0);
            __builtin_amdgcn_s_barrier();
            STAGE1(pB, hi, c0, k0 + 64);                 // Bh(s+1)
            STAGE1(pA, lo, c0, k0 + 64);                 // Bl(s+1)
        }
        char* tmp = pA; pA = pC; pC = tmp;               // pA<-Ah', pC<-Bl'
    }
#undef STAGE1
#undef PHASE

    // ---- epilogue: squared-distance space ----
    const float INF = __builtin_inff();

    // row pass: per row, min over this wave's 64 cols
#pragma unroll
    for (int m = 0; m < 4; ++m) {
#pragma unroll
        for (int reg = 0; reg < 4; ++reg) {
            const int row = wr * 64 + m * 16 + g2 * 4 + reg;
            const float si = rsq[row];
            const int rl = rlab[row];
            const float dp2 = rdp2a[row], dphi2 = rdp2b[row];
            float mn = INF, ms = INF;
#pragma unroll
            for (int nn = 0; nn < 4; ++nn) {
                const int col = wc * 64 + nn * 16 + lr;
                float sqd = fmaxf(si + csq[col] - 2.0f * acc[m][nn][reg], 0.0f);
                bool neq = (rl != clab[col]);
                mn = fminf(mn, neq ? sqd : INF);
                bool semi = neq && (sqd > dp2) && (sqd < dphi2);
                ms = fminf(ms, semi ? sqd : INF);
            }
#pragma unroll
            for (int msk = 1; msk <= 8; msk <<= 1) {
                mn = fminf(mn, __shfl_xor(mn, msk, 64));
                ms = fminf(ms, __shfl_xor(ms, msk, 64));
            }
            if (lr == 0) {
                atomicMin(&minneg[r0 + row], __float_as_int(mn));
                atomicMin(&minsemi[r0 + row], __float_as_int(ms));
            }
        }
    }

    // col pass: per col, min over this wave's 64 rows
#pragma unroll
    for (int n = 0; n < 4; ++n) {
        const int col = wc * 64 + n * 16 + lr;
        const float sj = csq[col];
        const int cl = clab[col];
        const float dp2 = cdp2a[col], dphi2 = cdp2b[col];
        float mn = INF, ms = INF;
#pragma unroll
        for (int m = 0; m < 4; ++m) {
#pragma unroll
            for (int reg = 0; reg < 4; ++reg) {
                const int row = wr * 64 + m * 16 + g2 * 4 + reg;
                float sqd = fmaxf(rsq[row] + sj - 2.0f * acc[m][n][reg], 0.0f);
                bool neq = (cl != rlab[row]);
                mn = fminf(mn, neq ? sqd : INF);
                bool semi = neq && (sqd > dp2) && (sqd < dphi2);
                ms = fminf(ms, semi ? sqd : INF);
            }
        }
        mn = fminf(mn, __shfl_xor(mn, 16, 64));
        mn = fminf(mn, __shfl_xor(mn, 32, 64));
        ms = fminf(ms, __shfl_xor(ms, 16, 64));
        ms = fminf(ms, __shfl_xor(ms, 32, 64));
        if (g2 == 0) {
            atomicMin(&minneg[c0 + col], __float_as_int(mn));
            atomicMin(&minsemi[c0 + col], __float_as_int(ms));
        }
    }
}

// ---------------------------------------------------------------------------
// final scalar reduction (minima are SQUARED distances)
// ---------------------------------------------------------------------------
__global__ __launch_bounds__(1024) void k_final(const float* __restrict__ dpos,
                                                const int* __restrict__ minneg,
                                                const int* __restrict__ minsemi,
                                                float* __restrict__ out) {
    __shared__ float ssum[1024];
    __shared__ float scnt[1024];
    int t = threadIdx.x;
    float s = 0.0f, cn = 0.0f;
    for (int i = t; i < N; i += 1024) {
        float dp = dpos[i];
        float mnq = __int_as_float(minneg[i]);
        float msq = __int_as_float(minsemi[i]);
        bool has_pos = dp >= 0.0f;
        bool has_neg = mnq < __builtin_inff();
        if (has_pos && has_neg) {
            float dnq = (msq < __builtin_inff()) ? msq : mnq;
            float dn = sqrtf(dnq);
            s += fmaxf(dp - dn + MARGIN, 0.0f);
            cn += 1.0f;
        }
    }
    ssum[t] = s;
    scnt[t] = cn;
    __syncthreads();
    for (int off = 512; off >= 1; off >>= 1) {
        if (t < off) {
            ssum[t] += ssum[t + off];
            scnt[t] += scnt[t + off];
        }
        __syncthreads();
    }
    if (t == 0) out[0] = ssum[0] / scnt[0];
}

// ---------------------------------------------------------------------------
extern "C" void kernel_launch(void* const* d_in, const int* in_sizes, int n_in,
                              void* d_out, int out_size, void* d_ws, size_t ws_size,
                              hipStream_t stream) {
    const float* x = (const float*)d_in[0];
    const int* labels = (const int*)d_in[1];
    float* out = (float*)d_out;

    // ws: sq[N] | dpos[N] | minneg[N] | minsemi[N] | cnt[512] | bkt[512*64]
    //     | hi[N*D] bf16 | lo[N*D] bf16
    float* sq = (float*)d_ws;
    float* dpos = sq + N;
    int* minneg = (int*)(dpos + N);
    int* minsemi = minneg + N;
    int* cnt = minsemi + N;
    int* bkt = cnt + 512;
    unsigned short* hi = (unsigned short*)(bkt + 512 * BCAP);
    unsigned short* lo = hi + (size_t)N * D;

    hipLaunchKernelGGL(k_zero, dim3(1), dim3(512), 0, stream, cnt);
    hipLaunchKernelGGL(k_conv, dim3(N * D / 4 / 256), dim3(256), 0, stream,
                       x, labels, hi, lo, cnt, bkt);
    hipLaunchKernelGGL(k_dpos, dim3(N / 4), dim3(256), 0, stream,
                       x, labels, cnt, bkt, sq, dpos, minneg, minsemi);
    hipLaunchKernelGGL(k_main, dim3(NTRI), dim3(256), 0, stream,
                       hi, lo, labels, sq, dpos, minneg, minsemi);
    hipLaunchKernelGGL(k_final, dim3(1), dim3(1024), 0, stream,
                       dpos, minneg, minsemi, out);
}